// Round 11
// baseline (307.870 us; speedup 1.0000x reference)
//
#include <hip/hip_runtime.h>
#include <cfloat>
#include <math.h>

// GATConv fused pipeline for MI355X.
// inputs: row[E] i32, col[E] i32, h[N,256] f32, W[256,128] f32, a_l[8,16] f32, a_r[8,16] f32
// output: relu(h_prime) [N,16,8] f32.
//
// R11:
//  prepack    : W -> MFMA B-fragments + coarse/fine-cell cursor init.
//  gemm_wh    : LDS-free MFMA bf16 gemm + fused Wh1/Wh2 epilogue (R9, proven).
//  push1      : LDS tile-reorder radix scatter into 196 coarse buckets (row>>8).
//               Waves write sorted bursts -> no per-lane 4B scatter (R10: 7x amp).
//  push2      : coarse slab -> 64 cells = (fine bucket row>>5) x (col-tile col/6250).
//               Dense runs (~144 edges/cell/WG).
//  bucket_gat : per 32-row bucket, CSR-in-LDS per (tile,row) key; processes col-tiles
//               in order -> gathers confined to a 1.6MB Whb slice (L2-resident).
//               acc/sm persist in registers across tiles (unnormalized online softmax,
//               single divide at end -- same math, reordered).

constexpr int IN_F  = 256;
constexpr int F     = 128;   // OUT*HEADS
constexpr int HEADS = 8;
constexpr int BS    = 32;    // rows per fine bucket
constexpr int BSH   = 5;
constexpr int NT    = 8;     // col tiles
constexpr int CCAP  = 256;   // per-cell capacity (avg 128, ~11 sigma)
constexpr int SLAB  = NT * CCAP;      // 2048 per fine bucket
constexpr int CSLAB = 9216;  // coarse slab capacity (avg 8192, ~11 sigma)
constexpr int PTILE = 4096;  // push1 tile size

typedef __attribute__((ext_vector_type(8))) short bf16x8;  // 8 bf16 in 4 VGPRs
typedef __attribute__((ext_vector_type(4))) float f32x4;

__device__ inline uint f2bf(float x) {              // f32 -> bf16 RNE (upper 16 bits)
    uint u = __float_as_uint(x);
    return (u + 0x7fffu + ((u >> 16) & 1u)) >> 16;
}
__device__ inline uint pack2(float a, float b) { return f2bf(a) | (f2bf(b) << 16); }

// ---------------- W prepack + cursor inits --------------------------------------
__global__ __launch_bounds__(256) void prepack(const float* __restrict__ W,
                                               uint4* __restrict__ Wf,
                                               int* __restrict__ cursorC,
                                               int* __restrict__ cursorF,
                                               int NC, int NBF)
{
    if (blockIdx.x == 0) {
        for (int i = threadIdx.x; i < NC; i += 256) cursorC[i] = i * CSLAB;
        for (int i = threadIdx.x; i < NBF * NT; i += 256)
            cursorF[i] = (i / NT) * SLAB + (i % NT) * CCAP;
    }
    int t = blockIdx.x * 256 + threadIdx.x;
    if (t >= 8 * 8 * 64) return;
    int ks = t >> 9, nt = (t >> 6) & 7, l = t & 63;
    int col = nt * 16 + (l & 15);
    int k0 = ks * 32 + (l >> 4) * 8;
    float v[8];
#pragma unroll
    for (int i = 0; i < 8; ++i) v[i] = W[(size_t)(k0 + i) * F + col];
    Wf[t] = make_uint4(pack2(v[0], v[1]), pack2(v[2], v[3]),
                       pack2(v[4], v[5]), pack2(v[6], v[7]));
}

// ---------------- GEMM: Wh = h @ W via MFMA, LDS-free, fused epilogue -----------
__global__ __launch_bounds__(256) void gemm_wh(
    const float* __restrict__ h, const uint4* __restrict__ Wf,
    const float* __restrict__ a_l, const float* __restrict__ a_r,
    uint* __restrict__ Whb, float* __restrict__ Wh1, float* __restrict__ Wh2, int n)
{
    const int tid = threadIdx.x;
    const int w = tid >> 6, l = tid & 63;
    const int r0 = blockIdx.x * 64 + w * 16;
    const int rA = min(r0 + (l & 15), n - 1);       // A row (m = lane&15)
    const int kb = (l >> 4) * 8;                    // A k-subgroup

    f32x4 acc[8];
#pragma unroll
    for (int i = 0; i < 8; ++i) acc[i] = (f32x4)0.f;

    const float* hp = &h[(size_t)rA * IN_F + kb];
    f32x4 a0 = __builtin_nontemporal_load((const f32x4*)hp);
    f32x4 a1 = __builtin_nontemporal_load((const f32x4*)(hp + 4));
    f32x4 na0, na1;

#pragma unroll
    for (int ks = 0; ks < 8; ++ks) {
        if (ks < 7) {
            na0 = __builtin_nontemporal_load((const f32x4*)(hp + (ks + 1) * 32));
            na1 = __builtin_nontemporal_load((const f32x4*)(hp + (ks + 1) * 32 + 4));
        }
        union { uint4 u; bf16x8 v; } A;
        A.u = make_uint4(pack2(a0[0], a0[1]), pack2(a0[2], a0[3]),
                         pack2(a1[0], a1[1]), pack2(a1[2], a1[3]));
        const uint4* wp = &Wf[ks * 512 + l];
#pragma unroll
        for (int nt = 0; nt < 8; ++nt) {
            union { uint4 u; bf16x8 v; } B;
            B.u = wp[nt * 64];
            acc[nt] = __builtin_amdgcn_mfma_f32_16x16x32_bf16(A.v, B.v, acc[nt], 0, 0, 0);
        }
        a0 = na0; a1 = na1;
    }

    const int c16 = l & 15;
    const int rowm = r0 + 4 * (l >> 4);
    float al[8], ar[8];
#pragma unroll
    for (int H = 0; H < 8; ++H) {
        al[H] = a_l[H * 16 + c16];
        ar[H] = a_r[H * 16 + c16];
    }
#pragma unroll
    for (int reg = 0; reg < 4; ++reg) {
        const int r = rowm + reg;
        float s1v[8], s2v[8];
#pragma unroll
        for (int H = 0; H < 8; ++H) {
            float wv = acc[H][reg];
            s1v[H] = wv * al[H];
            s2v[H] = wv * ar[H];
        }
#pragma unroll
        for (int d = 1; d <= 8; d <<= 1) {
#pragma unroll
            for (int H = 0; H < 8; ++H) {
                s1v[H] += __shfl_xor(s1v[H], d);
                s2v[H] += __shfl_xor(s2v[H], d);
            }
        }
        if (r < n) {
#pragma unroll
            for (int nt = 0; nt < 4; ++nt)
                Whb[(size_t)r * 64 + nt * 16 + c16] = pack2(acc[nt][reg], acc[nt + 4][reg]);
            if (c16 == 0) {
                *(float4*)&Wh1[r * 8]     = make_float4(s1v[0], s1v[1], s1v[2], s1v[3]);
                *(float4*)&Wh1[r * 8 + 4] = make_float4(s1v[4], s1v[5], s1v[6], s1v[7]);
                *(float4*)&Wh2[r * 8]     = make_float4(s2v[0], s2v[1], s2v[2], s2v[3]);
                *(float4*)&Wh2[r * 8 + 4] = make_float4(s2v[4], s2v[5], s2v[6], s2v[7]);
            }
        }
    }
}

// ---------------- push1: LDS tile-reorder scatter to coarse buckets (row>>8) ----
// One WG per 4096-edge tile: hist -> scan -> reserve -> LDS reorder -> burst out.
__global__ __launch_bounds__(256) void push1_kernel(
    const int* __restrict__ row, const int* __restrict__ col,
    int* __restrict__ cursorC, uint* __restrict__ cpairs, int E)
{
    __shared__ uint stage[PTILE];
    __shared__ int hist[256], st[256], cur[256], gbase[256];
    const int t = threadIdx.x;
    const int i0 = blockIdx.x * PTILE;
    const int cnt = min(PTILE, E - i0);
    hist[t] = 0;
    __syncthreads();

    uint u[PTILE / 256];
#pragma unroll
    for (int j = 0; j < PTILE / 256; ++j) {
        const int idx = t + j * 256;
        if (idx < cnt) {
            int r = row[i0 + idx], c = col[i0 + idx];
            u[j] = ((uint)(r >> 8) << 24) | ((uint)c << 8) | (uint)(r & 255);
            atomicAdd(&hist[r >> 8], 1);
        } else u[j] = 0xFFFFFFFFu;
    }
    __syncthreads();

    const int v = hist[t];
    st[t] = v;
    __syncthreads();
    for (int off = 1; off < 256; off <<= 1) {
        int x = (t >= off) ? st[t - off] : 0;
        __syncthreads();
        st[t] += x;
        __syncthreads();
    }
    cur[t] = st[t] - v;                    // exclusive start within tile
    if (v) gbase[t] = atomicAdd(&cursorC[t], v);
    __syncthreads();

#pragma unroll
    for (int j = 0; j < PTILE / 256; ++j) {
        if (u[j] != 0xFFFFFFFFu) {
            int k = u[j] >> 24;
            int pos = atomicAdd(&cur[k], 1);
            stage[pos] = u[j];
        }
    }
    __syncthreads();

    for (int p = t; p < cnt; p += 256) {
        uint w = stage[p];
        int k = w >> 24;
        int lstart = st[k] - hist[k];
        __builtin_nontemporal_store(w & 0xFFFFFFu, &cpairs[gbase[k] + (p - lstart)]);
    }
}

// ---------------- push2: coarse slab -> 64 cells (fine bucket x col-tile) -------
__global__ __launch_bounds__(256) void push2_kernel(
    const uint* __restrict__ cpairs, const int* __restrict__ cursorC,
    int* __restrict__ cursorF, uint* __restrict__ pairs, int RPT)
{
    __shared__ int hl[64], cur64[64];
    const int c = blockIdx.x;
    const int p0 = c * CSLAB;
    const int ec = cursorC[c] - p0;
    const int t = threadIdx.x;
    if (t < 64) hl[t] = 0;
    __syncthreads();
    for (int p = t; p < ec; p += 256) {
        uint u = cpairs[p0 + p];
        int key = (int)((u >> 5) & 7) * NT + (int)((u >> 8) / (uint)RPT);
        atomicAdd(&hl[key], 1);
    }
    __syncthreads();
    if (t < 64)
        cur64[t] = hl[t] ? atomicAdd(&cursorF[c * 64 + t], hl[t]) : 0;
    __syncthreads();
    for (int p = t; p < ec; p += 256) {
        uint u = cpairs[p0 + p];
        uint colv = u >> 8;
        int key = (int)((u >> 5) & 7) * NT + (int)(colv / (uint)RPT);
        int pos = atomicAdd(&cur64[key], 1);
        __builtin_nontemporal_store((colv << 5) | (u & 31), &pairs[pos]);
    }
}

// ---------------- fused CSR-in-LDS + col-tiled softmax/aggregate ----------------
// One WG per 32-row bucket; keys = tile*32 + row_local (256 keys). Phase B walks
// tiles in order so the Whb gather stays within a 1.6MB L2-resident slice.
__global__ __launch_bounds__(256) void bucket_gat(
    const uint* __restrict__ pairs, const int* __restrict__ cursorF,
    const uint* __restrict__ Whb, const float* __restrict__ Wh1,
    const float* __restrict__ Wh2, float* __restrict__ out, int n)
{
    __shared__ uint cols_l[SLAB];                   // 8 KB bucket col list
    __shared__ int cnt_l[256], st0[256], cur_l[256];
    const int t = threadIdx.x;
    const int b = blockIdx.x;

    cnt_l[t] = 0;
    __syncthreads();
#pragma unroll 1
    for (int tl = 0; tl < NT; ++tl) {
        const int base = b * SLAB + tl * CCAP;
        const int ec = cursorF[b * NT + tl] - base;
        for (int p = t; p < ec; p += 256)
            atomicAdd(&cnt_l[tl * 32 + (pairs[base + p] & 31)], 1);
    }
    __syncthreads();
    const int v = cnt_l[t];
    st0[t] = v;
    __syncthreads();
    for (int off = 1; off < 256; off <<= 1) {
        int x = (t >= off) ? st0[t - off] : 0;
        __syncthreads();
        st0[t] += x;
        __syncthreads();
    }
    st0[t] -= v;                                    // exclusive
    cur_l[t] = st0[t];
    __syncthreads();
#pragma unroll 1
    for (int tl = 0; tl < NT; ++tl) {
        const int base = b * SLAB + tl * CCAP;
        const int ec = cursorF[b * NT + tl] - base;
        for (int p = t; p < ec; p += 256) {
            uint u = pairs[base + p];
            int slot = atomicAdd(&cur_l[tl * 32 + (u & 31)], 1);
            cols_l[slot] = u >> 5;
        }
    }
    __syncthreads();

    const int wv = t >> 6, lane = t & 63;
    const int h8 = lane & 7, es = lane >> 3;
    float acc0[8], acc1[8], sm[8], w1r[8];
#pragma unroll
    for (int i = 0; i < 8; ++i) {
        acc0[i] = acc1[i] = sm[i] = 0.f;
        const int r = (b << BSH) + wv * 8 + i;
        w1r[i] = (r < n) ? Wh1[r * HEADS + h8] : 0.f;
    }

#pragma unroll 1
    for (int tl = 0; tl < NT; ++tl) {
#pragma unroll
        for (int i = 0; i < 8; ++i) {
            const int key = tl * 32 + wv * 8 + i;
            const int st = st0[key];
            const int deg = cnt_l[key];
            const float w1 = w1r[i];
            for (int g = 0; g < deg; g += 8) {
                const int kk = g + es;
                const bool valid = kk < deg;
                const uint c = cols_l[st + (valid ? kk : deg - 1)];
                float e = w1 + Wh2[c * HEADS + h8];
                e = e > 0.f ? e : 0.2f * e;
                e = fminf(e, 60.f);                 // overflow guard
                const float ex = valid ? __expf(e) : 0.f;
                sm[i] += ex;
                const int m8 = deg - g;
                if (m8 >= 8) {
#pragma unroll
                    for (int k = 0; k < 8; ++k) {
                        float pA = __shfl(ex, k * 8 + h8);
                        uint ck = cols_l[st + g + k];
                        uint wb = Whb[((size_t)ck << 6) + lane];
                        acc0[i] = fmaf(pA, __uint_as_float(wb << 16), acc0[i]);
                        acc1[i] = fmaf(pA, __uint_as_float(wb & 0xffff0000u), acc1[i]);
                    }
                } else {
                    for (int k = 0; k < m8; ++k) {
                        float pA = __shfl(ex, k * 8 + h8);
                        uint ck = cols_l[st + g + k];
                        uint wb = Whb[((size_t)ck << 6) + lane];
                        acc0[i] = fmaf(pA, __uint_as_float(wb << 16), acc0[i]);
                        acc1[i] = fmaf(pA, __uint_as_float(wb & 0xffff0000u), acc1[i]);
                    }
                }
            }
        }
    }

#pragma unroll
    for (int i = 0; i < 8; ++i) {
        float s = sm[i];
        s += __shfl_xor(s, 8);
        s += __shfl_xor(s, 16);
        s += __shfl_xor(s, 32);
        const int r = (b << BSH) + wv * 8 + i;
        if (r < n) {
            const float inv = (s > 0.f) ? 1.f / s : 0.f;
            __builtin_nontemporal_store(fmaxf(acc0[i] * inv, 0.f),
                                        &out[(size_t)r * F + lane]);
            __builtin_nontemporal_store(fmaxf(acc1[i] * inv, 0.f),
                                        &out[(size_t)r * F + 64 + lane]);
        }
    }
}

// ---------------- launch ----------------
extern "C" void kernel_launch(void* const* d_in, const int* in_sizes, int n_in,
                              void* d_out, int out_size, void* d_ws, size_t ws_size,
                              hipStream_t stream)
{
    const int* row = (const int*)d_in[0];
    const int* col = (const int*)d_in[1];
    const float* h   = (const float*)d_in[2];
    const float* W   = (const float*)d_in[3];
    const float* a_l = (const float*)d_in[4];
    const float* a_r = (const float*)d_in[5];
    const int E = in_sizes[0];
    const int n = in_sizes[2] / IN_F;
    float* out = (float*)d_out;
    const int NBF = (n + BS - 1) >> BSH;                // fine buckets (1563)
    const int NC  = (n + 255) >> 8;                     // coarse buckets (196)
    const int RPT = (n + NT - 1) / NT;                  // rows per col tile (6250)

    char* p = (char*)d_ws;
    auto alloc = [&](size_t bytes) -> char* {
        char* q = p;
        p += (bytes + 255) & ~(size_t)255;
        return q;
    };
    uint*  Whb     = (uint*)alloc((size_t)n * 64 * 4);  // paired bf16 cols (l, l+64)
    float* Wh1     = (float*)alloc((size_t)n * HEADS * 4);
    float* Wh2     = (float*)alloc((size_t)n * HEADS * 4);
    uint4* Wf      = (uint4*)alloc(8 * 8 * 64 * 16);    // prepacked W fragments
    int*   cursorC = (int*)alloc((size_t)NC * 4);
    int*   cursorF = (int*)alloc((size_t)NBF * NT * 4);
    uint*  cpairs  = (uint*)alloc((size_t)NC * CSLAB * 4);
    uint*  pairs   = (uint*)alloc((size_t)NBF * SLAB * 4);

    prepack<<<16, 256, 0, stream>>>(W, Wf, cursorC, cursorF, NC, NBF);
    gemm_wh<<<(n + 63) / 64, 256, 0, stream>>>(h, Wf, a_l, a_r, Whb, Wh1, Wh2, n);
    push1_kernel<<<(E + PTILE - 1) / PTILE, 256, 0, stream>>>(row, col, cursorC, cpairs, E);
    push2_kernel<<<NC, 256, 0, stream>>>(cpairs, cursorC, cursorF, pairs, RPT);
    bucket_gat<<<NBF, 256, 0, stream>>>(pairs, cursorF, Whb, Wh1, Wh2, out, n);
}

// Round 12
// 150.133 us; speedup vs baseline: 2.0507x; 2.0507x over previous
//
#include <hip/hip_runtime.h>
#include <cfloat>
#include <math.h>

// GATConv fused pipeline for MI355X.
// inputs: row[E] i32, col[E] i32, h[N,256] f32, W[256,128] f32, a_l[8,16] f32, a_r[8,16] f32
// output: relu(h_prime) [N,16,8] f32.
//
// R12 (lessons: R11 showed gat is LATENCY-bound, not BW-bound -> keep R9 structure;
//      R10 counters showed working set is L3-resident -> gemm was latency-bound on
//      its depth-1 A prefetch):
//  prepack    : W -> MFMA B-fragments + cursor inits.
//  gemm_wh    : MFMA bf16, FULL A preload (16 loads issued back-to-back, one
//               latency exposure per wave instead of 8). B from L2 (64KB table).
//  push1      : LDS tile-reorder radix scatter -> 196 coarse buckets (row>>8),
//               dense burst writes (R11 kernel, proven quiet).
//  push2      : coarse slab -> 8 fine slabs (dense both sides, R10 kernel).
//  bucket_gat : R9 proven 32-row bucket CSR-in-LDS + softmax + gather (~72us).

constexpr int IN_F  = 256;
constexpr int F     = 128;   // OUT*HEADS
constexpr int HEADS = 8;
constexpr int BS    = 32;    // rows per fine bucket
constexpr int BSH   = 5;
constexpr int SLAB  = 2048;  // fine slab capacity (avg 1024, ~32 sigma)
constexpr int CSLAB = 9216;  // coarse slab capacity (avg 8192, ~11 sigma)
constexpr int PTILE = 4096;  // push1 tile size

typedef __attribute__((ext_vector_type(8))) short bf16x8;  // 8 bf16 in 4 VGPRs
typedef __attribute__((ext_vector_type(4))) float f32x4;

__device__ inline uint f2bf(float x) {              // f32 -> bf16 RNE (upper 16 bits)
    uint u = __float_as_uint(x);
    return (u + 0x7fffu + ((u >> 16) & 1u)) >> 16;
}
__device__ inline uint pack2(float a, float b) { return f2bf(a) | (f2bf(b) << 16); }

// ---------------- W prepack + cursor inits --------------------------------------
__global__ __launch_bounds__(256) void prepack(const float* __restrict__ W,
                                               uint4* __restrict__ Wf,
                                               int* __restrict__ cursorC,
                                               int* __restrict__ cursorF,
                                               int NC, int NBF)
{
    if (blockIdx.x == 0) {
        for (int i = threadIdx.x; i < NC; i += 256) cursorC[i] = i * CSLAB;
        for (int i = threadIdx.x; i < NBF; i += 256) cursorF[i] = i * SLAB;
    }
    int t = blockIdx.x * 256 + threadIdx.x;
    if (t >= 8 * 8 * 64) return;
    int ks = t >> 9, nt = (t >> 6) & 7, l = t & 63;
    int col = nt * 16 + (l & 15);
    int k0 = ks * 32 + (l >> 4) * 8;
    float v[8];
#pragma unroll
    for (int i = 0; i < 8; ++i) v[i] = W[(size_t)(k0 + i) * F + col];
    Wf[t] = make_uint4(pack2(v[0], v[1]), pack2(v[2], v[3]),
                       pack2(v[4], v[5]), pack2(v[6], v[7]));
}

// ---------------- GEMM: Wh = h @ W via MFMA, full A preload ---------------------
// 256 threads = 4 waves; wave w: rows [bid*64 + w*16, +16). One load burst/wave.
__global__ __launch_bounds__(256) void gemm_wh(
    const float* __restrict__ h, const uint4* __restrict__ Wf,
    const float* __restrict__ a_l, const float* __restrict__ a_r,
    uint* __restrict__ Whb, float* __restrict__ Wh1, float* __restrict__ Wh2, int n)
{
    const int tid = threadIdx.x;
    const int w = tid >> 6, l = tid & 63;
    const int r0 = blockIdx.x * 64 + w * 16;
    const int rA = min(r0 + (l & 15), n - 1);       // A row (m = lane&15)
    const int kb = (l >> 4) * 8;                    // A k-subgroup

    const float* hp = &h[(size_t)rA * IN_F + kb];
    f32x4 af[16];
#pragma unroll
    for (int ks = 0; ks < 8; ++ks) {                // 16 loads, back-to-back
        af[2 * ks]     = __builtin_nontemporal_load((const f32x4*)(hp + ks * 32));
        af[2 * ks + 1] = __builtin_nontemporal_load((const f32x4*)(hp + ks * 32 + 4));
    }
    uint4 Abf[8];
#pragma unroll
    for (int ks = 0; ks < 8; ++ks) {
        f32x4 a0 = af[2 * ks], a1 = af[2 * ks + 1];
        Abf[ks] = make_uint4(pack2(a0[0], a0[1]), pack2(a0[2], a0[3]),
                             pack2(a1[0], a1[1]), pack2(a1[2], a1[3]));
    }

    f32x4 acc[8];
#pragma unroll
    for (int i = 0; i < 8; ++i) acc[i] = (f32x4)0.f;

#pragma unroll
    for (int ks = 0; ks < 8; ++ks) {
        union { uint4 u; bf16x8 v; } A;
        A.u = Abf[ks];
        const uint4* wp = &Wf[ks * 512 + l];
#pragma unroll
        for (int nt = 0; nt < 8; ++nt) {
            union { uint4 u; bf16x8 v; } B;
            B.u = wp[nt * 64];
            acc[nt] = __builtin_amdgcn_mfma_f32_16x16x32_bf16(A.v, B.v, acc[nt], 0, 0, 0);
        }
    }

    // epilogue. D layout: m = 4*(l>>4)+reg, nn = l&15; col = nt*16+nn, head = nt.
    const int c16 = l & 15;
    const int rowm = r0 + 4 * (l >> 4);
    float al[8], ar[8];
#pragma unroll
    for (int H = 0; H < 8; ++H) {
        al[H] = a_l[H * 16 + c16];
        ar[H] = a_r[H * 16 + c16];
    }
#pragma unroll
    for (int reg = 0; reg < 4; ++reg) {
        const int r = rowm + reg;
        float s1v[8], s2v[8];
#pragma unroll
        for (int H = 0; H < 8; ++H) {
            float wv = acc[H][reg];
            s1v[H] = wv * al[H];
            s2v[H] = wv * ar[H];
        }
#pragma unroll
        for (int d = 1; d <= 8; d <<= 1) {
#pragma unroll
            for (int H = 0; H < 8; ++H) {
                s1v[H] += __shfl_xor(s1v[H], d);
                s2v[H] += __shfl_xor(s2v[H], d);
            }
        }
        if (r < n) {
#pragma unroll
            for (int nt = 0; nt < 4; ++nt)
                Whb[(size_t)r * 64 + nt * 16 + c16] = pack2(acc[nt][reg], acc[nt + 4][reg]);
            if (c16 == 0) {
                *(float4*)&Wh1[r * 8]     = make_float4(s1v[0], s1v[1], s1v[2], s1v[3]);
                *(float4*)&Wh1[r * 8 + 4] = make_float4(s1v[4], s1v[5], s1v[6], s1v[7]);
                *(float4*)&Wh2[r * 8]     = make_float4(s2v[0], s2v[1], s2v[2], s2v[3]);
                *(float4*)&Wh2[r * 8 + 4] = make_float4(s2v[4], s2v[5], s2v[6], s2v[7]);
            }
        }
    }
}

// ---------------- push1: LDS tile-reorder scatter to coarse buckets (row>>8) ----
// One WG per 4096-edge tile: hist -> scan -> reserve -> LDS reorder -> burst out.
__global__ __launch_bounds__(256) void push1_kernel(
    const int* __restrict__ row, const int* __restrict__ col,
    int* __restrict__ cursorC, uint* __restrict__ cpairs, int E)
{
    __shared__ uint stage[PTILE];
    __shared__ int hist[256], st[256], cur[256], gbase[256];
    const int t = threadIdx.x;
    const int i0 = blockIdx.x * PTILE;
    const int cnt = min(PTILE, E - i0);
    hist[t] = 0;
    __syncthreads();

    uint u[PTILE / 256];
#pragma unroll
    for (int j = 0; j < PTILE / 256; ++j) {
        const int idx = t + j * 256;
        if (idx < cnt) {
            int r = row[i0 + idx], c = col[i0 + idx];
            u[j] = ((uint)(r >> 8) << 24) | ((uint)c << 8) | (uint)(r & 255);
            atomicAdd(&hist[r >> 8], 1);
        } else u[j] = 0xFFFFFFFFu;
    }
    __syncthreads();

    const int v = hist[t];
    st[t] = v;
    __syncthreads();
    for (int off = 1; off < 256; off <<= 1) {
        int x = (t >= off) ? st[t - off] : 0;
        __syncthreads();
        st[t] += x;
        __syncthreads();
    }
    cur[t] = st[t] - v;                    // exclusive start within tile
    if (v) gbase[t] = atomicAdd(&cursorC[t], v);
    __syncthreads();

#pragma unroll
    for (int j = 0; j < PTILE / 256; ++j) {
        if (u[j] != 0xFFFFFFFFu) {
            int k = u[j] >> 24;
            int pos = atomicAdd(&cur[k], 1);
            stage[pos] = u[j];
        }
    }
    __syncthreads();

    for (int p = t; p < cnt; p += 256) {
        uint wv = stage[p];
        int k = wv >> 24;
        int lstart = st[k] - hist[k];
        __builtin_nontemporal_store(wv & 0xFFFFFFu, &cpairs[gbase[k] + (p - lstart)]);
    }
}

// ---------------- push2: coarse slab -> 8 fine slabs (dense both sides) ---------
__global__ __launch_bounds__(256) void push2_kernel(
    const uint* __restrict__ cpairs, const int* __restrict__ cursorC,
    int* __restrict__ cursorF, uint* __restrict__ pairs)
{
    __shared__ int hl[8];
    __shared__ int cur8[8];
    const int c = blockIdx.x;
    const int p0 = c * CSLAB;
    const int ec = cursorC[c] - p0;
    const int t = threadIdx.x;
    if (t < 8) hl[t] = 0;
    __syncthreads();
    for (int p = t; p < ec; p += 256)
        atomicAdd(&hl[(cpairs[p0 + p] >> 5) & 7], 1);
    __syncthreads();
    if (t < 8)
        cur8[t] = hl[t] ? atomicAdd(&cursorF[c * 8 + t], hl[t]) : 0;
    __syncthreads();
    for (int p = t; p < ec; p += 256) {
        uint u = cpairs[p0 + p];
        int pos = atomicAdd(&cur8[(u >> 5) & 7], 1);
        // coarse pair (col<<8)|(row&255) -> fine pair (col<<5)|(row&31)
        __builtin_nontemporal_store(((u >> 8) << 5) | (u & 31), &pairs[pos]);
    }
}

// ---------------- fused CSR-in-LDS + softmax + aggregate (R9 proven) ------------
// One WG (4 waves) per 32-row bucket. Phase A: count/scan/scatter cols into LDS.
// Phase B: wave w processes rows w*8..w*8+7 with the 8-edge-slot gather loop.
__global__ __launch_bounds__(256) void bucket_gat(
    const uint* __restrict__ pairs, const int* __restrict__ cursorF,
    const uint* __restrict__ Whb, const float* __restrict__ Wh1,
    const float* __restrict__ Wh2, float* __restrict__ out, int n)
{
    __shared__ uint cols_l[SLAB];                   // 8 KB bucket col list
    __shared__ int cnt_l[BS], st0[BS], cur_l[BS];
    const int t = threadIdx.x;
    const int b = blockIdx.x;
    const int p0 = b * SLAB;
    const int ec = cursorF[b] - p0;                 // edges in this bucket

    if (t < BS) cnt_l[t] = 0;
    __syncthreads();
    for (int p = t; p < ec; p += 256)
        atomicAdd(&cnt_l[pairs[p0 + p] & (BS - 1)], 1);
    __syncthreads();
    if (t < BS) {
        int v = cnt_l[t];
        int inc = v;                                // inclusive scan over 32 lanes
#pragma unroll
        for (int off = 1; off < BS; off <<= 1) {
            int x = __shfl_up(inc, off);
            if (t >= off) inc += x;
        }
        st0[t] = inc - v;
        cur_l[t] = inc - v;
    }
    __syncthreads();
    for (int p = t; p < ec; p += 256) {
        uint u = pairs[p0 + p];
        int slot = atomicAdd(&cur_l[u & (BS - 1)], 1);
        cols_l[slot] = u >> BSH;
    }
    __syncthreads();

    const int wv = t >> 6, lane = t & 63;
    const int h8 = lane & 7, es = lane >> 3;
#pragma unroll 1
    for (int i = 0; i < 8; ++i) {
        const int rl = wv * 8 + i;
        const int r = (b << BSH) + rl;
        if (r >= n) continue;
        const float w1 = Wh1[r * HEADS + h8];
        const int st = st0[rl];
        const int deg = cnt_l[rl];

        float acc0 = 0.f, acc1 = 0.f, sm = 0.f;
        for (int g = 0; g < deg; g += 8) {
            const int kk = g + es;
            const bool valid = kk < deg;
            const uint c = cols_l[st + (valid ? kk : deg - 1)];
            float e = w1 + Wh2[c * HEADS + h8];
            e = e > 0.f ? e : 0.2f * e;
            e = fminf(e, 60.f);                     // overflow guard
            const float ex = valid ? __expf(e) : 0.f;
            sm += ex;
            const int m8 = deg - g;
            if (m8 >= 8) {
#pragma unroll
                for (int k = 0; k < 8; ++k) {
                    float pA = __shfl(ex, k * 8 + h8);
                    uint ck = cols_l[st + g + k];
                    uint wb = Whb[((size_t)ck << 6) + lane];
                    acc0 = fmaf(pA, __uint_as_float(wb << 16), acc0);
                    acc1 = fmaf(pA, __uint_as_float(wb & 0xffff0000u), acc1);
                }
            } else {
                for (int k = 0; k < m8; ++k) {
                    float pA = __shfl(ex, k * 8 + h8);
                    uint ck = cols_l[st + g + k];
                    uint wb = Whb[((size_t)ck << 6) + lane];
                    acc0 = fmaf(pA, __uint_as_float(wb << 16), acc0);
                    acc1 = fmaf(pA, __uint_as_float(wb & 0xffff0000u), acc1);
                }
            }
        }
        sm += __shfl_xor(sm, 8);
        sm += __shfl_xor(sm, 16);
        sm += __shfl_xor(sm, 32);
        const float inv = (deg > 0) ? 1.f / sm : 0.f;
        __builtin_nontemporal_store(fmaxf(acc0 * inv, 0.f), &out[(size_t)r * F + lane]);
        __builtin_nontemporal_store(fmaxf(acc1 * inv, 0.f), &out[(size_t)r * F + 64 + lane]);
    }
}

// ---------------- launch ----------------
extern "C" void kernel_launch(void* const* d_in, const int* in_sizes, int n_in,
                              void* d_out, int out_size, void* d_ws, size_t ws_size,
                              hipStream_t stream)
{
    const int* row = (const int*)d_in[0];
    const int* col = (const int*)d_in[1];
    const float* h   = (const float*)d_in[2];
    const float* W   = (const float*)d_in[3];
    const float* a_l = (const float*)d_in[4];
    const float* a_r = (const float*)d_in[5];
    const int E = in_sizes[0];
    const int n = in_sizes[2] / IN_F;
    float* out = (float*)d_out;
    const int NBF = (n + BS - 1) >> BSH;                // fine buckets (1563)
    const int NC  = (n + 255) >> 8;                     // coarse buckets (196)

    char* p = (char*)d_ws;
    auto alloc = [&](size_t bytes) -> char* {
        char* q = p;
        p += (bytes + 255) & ~(size_t)255;
        return q;
    };
    uint*  Whb     = (uint*)alloc((size_t)n * 64 * 4);  // paired bf16 cols (l, l+64)
    float* Wh1     = (float*)alloc((size_t)n * HEADS * 4);
    float* Wh2     = (float*)alloc((size_t)n * HEADS * 4);
    uint4* Wf      = (uint4*)alloc(8 * 8 * 64 * 16);    // prepacked W fragments
    int*   cursorC = (int*)alloc((size_t)NC * 4);
    int*   cursorF = (int*)alloc((size_t)NBF * 4);
    uint*  cpairs  = (uint*)alloc((size_t)NC * CSLAB * 4);
    uint*  pairs   = (uint*)alloc((size_t)NBF * SLAB * 4);

    prepack<<<16, 256, 0, stream>>>(W, Wf, cursorC, cursorF, NC, NBF);
    gemm_wh<<<(n + 63) / 64, 256, 0, stream>>>(h, Wf, a_l, a_r, Whb, Wh1, Wh2, n);
    push1_kernel<<<(E + PTILE - 1) / PTILE, 256, 0, stream>>>(row, col, cursorC, cpairs, E);
    push2_kernel<<<NC, 256, 0, stream>>>(cpairs, cursorC, cursorF, pairs);
    bucket_gat<<<NBF, 256, 0, stream>>>(pairs, cursorF, Whb, Wh1, Wh2, out, n);
}